// Round 12
// baseline (309.002 us; speedup 1.0000x reference)
//
#include <hip/hip_runtime.h>

#define D_MODEL 512
#define NHEADS 8
#define DH 64
#define BATCH 2
#define SEQ 4096
#define MTOT (BATCH*SEQ)   // 8192

typedef __attribute__((ext_vector_type(8))) short bf16x8;
typedef __attribute__((ext_vector_type(4))) short s16x4;
typedef __attribute__((ext_vector_type(4))) float f32x4;

__device__ __forceinline__ unsigned short f2b(float f) {
  unsigned int u = __float_as_uint(f);
  u = (u + 0x7fffu + ((u >> 16) & 1u)) >> 16;
  return (unsigned short)u;
}

__device__ __forceinline__ float fexp2(float x) {
  return __builtin_amdgcn_exp2f(x);
}

// pack 2 f32 -> 2 bf16 in one u32 (lo = a, hi = b)
__device__ __forceinline__ unsigned int cvtpk_bf16(float a, float b) {
  unsigned int r;
  asm("v_cvt_pk_bf16_f32 %0, %1, %2" : "=v"(r) : "v"(a), "v"(b));
  return r;
}

// hardware transpose read: tile_base = addr & ~127 (4x16 bf16 row-major tile),
// col = (addr>>3)&15; lane receives the 4 bf16 of that column. (r10-verified)
__device__ __forceinline__ void tr16(unsigned addr, s16x4& d) {
  asm volatile("ds_read_b64_tr_b16 %0, %1" : "=v"(d) : "v"(addr));
}

// ---------------- conversion kernels ----------------

__global__ void cvt_x_kernel(const float* __restrict__ X,
                             unsigned short* __restrict__ Xb, int n) {
  int i = (blockIdx.x * blockDim.x + threadIdx.x) * 8;
  if (i >= n) return;
  const float4* s = (const float4*)(X + i);
  float4 v0 = s[0], v1 = s[1];
  union { bf16x8 v; unsigned short u[8]; } r;
  r.u[0] = f2b(v0.x); r.u[1] = f2b(v0.y); r.u[2] = f2b(v0.z); r.u[3] = f2b(v0.w);
  r.u[4] = f2b(v1.x); r.u[5] = f2b(v1.y); r.u[6] = f2b(v1.z); r.u[7] = f2b(v1.w);
  *(bf16x8*)(Xb + i) = r.v;
}

__global__ void cvt_w_kernel(const float* __restrict__ W0, const float* __restrict__ W1,
                             const float* __restrict__ W2, const float* __restrict__ W3,
                             unsigned short* __restrict__ Wt) {
  const float* Ws[4] = {W0, W1, W2, W3};
  const float* W = Ws[blockIdx.y];
  int t = blockIdx.x * blockDim.x + threadIdx.x;
  int k = t >> 9, n = t & 511;
  Wt[(size_t)blockIdx.y * (512*512) + (size_t)n * 512 + k] = f2b(W[t]);
}

// ---------------- 128x128 bf16 MFMA GEMM ----------------
__global__ __launch_bounds__(256) void gemm128_kernel(
    const unsigned short* __restrict__ A,
    const unsigned short* __restrict__ WtAll,
    unsigned short* __restrict__ qkv,
    float* __restrict__ outF,
    int modeParam) {
  int mode = (modeParam < 0) ? (int)blockIdx.z : modeParam;
  const unsigned short* Wt = WtAll + (size_t)((modeParam < 0) ? blockIdx.z : 0) * (512*512);

  __shared__ __align__(16) unsigned short Alds[128][72];
  __shared__ __align__(16) unsigned short Blds[128][72];

  int t = threadIdx.x;
  int lane = t & 63, wave = t >> 6;
  int wr = wave >> 1, wc = wave & 1;
  int lr = lane & 15, lg = lane >> 4;
  int mBase = blockIdx.x * 128;
  int nBase = blockIdx.y * 128;

  f32x4 zero = {0.f, 0.f, 0.f, 0.f};
  f32x4 acc[4][4];
#pragma unroll
  for (int i = 0; i < 4; i++)
#pragma unroll
    for (int j = 0; j < 4; j++) acc[i][j] = zero;

  int seg = t & 7, r0 = t >> 3;

  for (int k0 = 0; k0 < 512; k0 += 64) {
#pragma unroll
    for (int p = 0; p < 4; ++p) {
      int row = r0 + p * 32;
      *(int4*)&Alds[row][seg * 8] =
          *(const int4*)(A + (size_t)(mBase + row) * 512 + k0 + seg * 8);
      *(int4*)&Blds[row][seg * 8] =
          *(const int4*)(Wt + (size_t)(nBase + row) * 512 + k0 + seg * 8);
    }
    __syncthreads();
#pragma unroll
    for (int kk = 0; kk < 64; kk += 32) {
      bf16x8 afr[4], bfr[4];
#pragma unroll
      for (int mi = 0; mi < 4; mi++)
        afr[mi] = *(const bf16x8*)&Alds[wr * 64 + mi * 16 + lr][kk + lg * 8];
#pragma unroll
      for (int ni = 0; ni < 4; ni++)
        bfr[ni] = *(const bf16x8*)&Blds[wc * 64 + ni * 16 + lr][kk + lg * 8];
#pragma unroll
      for (int mi = 0; mi < 4; mi++)
#pragma unroll
        for (int ni = 0; ni < 4; ni++)
          acc[mi][ni] = __builtin_amdgcn_mfma_f32_16x16x32_bf16(
              afr[mi], bfr[ni], acc[mi][ni], 0, 0, 0);
    }
    __syncthreads();
  }

#pragma unroll
  for (int mi = 0; mi < 4; mi++) {
#pragma unroll
    for (int ni = 0; ni < 4; ni++) {
#pragma unroll
      for (int rg = 0; rg < 4; rg++) {
        int r = mBase + wr * 64 + mi * 16 + lg * 4 + rg;
        int c = nBase + wc * 64 + ni * 16 + lr;
        float v = acc[mi][ni][rg];
        if (mode < 3) {
          int b = r >> 12, s = r & 4095, h = c >> 6, d = c & 63;
          qkv[(size_t)mode * ((size_t)MTOT * 512) +
              ((((size_t)b * NHEADS + h) * SEQ + s) * DH + d)] = f2b(v);
        } else {
          outF[(size_t)r * 512 + c] = v;
        }
      }
    }
  }
}

// ---------------- flash attention (r10 structure + K-from-global + b64 PT) ----
// grid 512 flat, block 512 (8 waves), 16 q-rows/wave. KV tiles of 64 keys.
// K fragments DIRECT from global (L1-resident, prefetched 1 tile ahead); no
// K LDS. V double-buffered in LDS (subtiled for tr16), barrier at r10's
// position (right after staging). Swapped-QK lane-local softmax.
__global__ __launch_bounds__(512) void attn_kernel(
    const unsigned short* __restrict__ Qb,
    const unsigned short* __restrict__ Kb,
    const unsigned short* __restrict__ Vb,
    unsigned short* __restrict__ CTX) {
  int flat = blockIdx.x;
  int xcd = flat & 7, jj = flat >> 3;
  int bh = xcd + ((jj >> 5) << 3);   // 2 heads per XCD, bijective (512%8==0)
  int qc = jj & 31;
  int b = bh >> 3, h = bh & 7;
  const unsigned short* Qp = Qb + (size_t)bh * SEQ * DH;
  const unsigned short* Kp = Kb + (size_t)bh * SEQ * DH;
  const unsigned short* Vp = Vb + (size_t)bh * SEQ * DH;

  __shared__ __align__(128) unsigned short Vl[2][4096];     // subtiled V
  __shared__ __align__(128) unsigned short PT[8][16][72];   // per wave

  int t = threadIdx.x;            // 0..511
  int lane = t & 63, wave = t >> 6;
  int lr = lane & 15, lg = lane >> 4;
  int q0 = qc * 128 + wave * 16;

  // Q fragments (B operand): col=q=lr, k = kk*32 + 8*lg + j
  bf16x8 aq[2];
#pragma unroll
  for (int kk = 0; kk < 2; ++kk)
    aq[kk] = *(const bf16x8*)(Qp + (size_t)(q0 + lr) * DH + kk * 32 + lg * 8);

  f32x4 zero = {0.f, 0.f, 0.f, 0.f};
  f32x4 o[4];
#pragma unroll
  for (int dt = 0; dt < 4; dt++) o[dt] = zero;
  float m2 = -1e30f, lsum = 0.f;

  const float c2 = 0.125f * 1.44269504088896340736f;

  // V staging: 512 threads, ONE b128 each: row = t>>3, seg = t&7
  int srow = t >> 3, sseg = t & 7;
  int vdst = ((srow >> 2) * 4 + (sseg >> 1)) * 64 + (srow & 3) * 16 + (sseg & 1) * 8;
  const int NT = SEQ / 64;

  unsigned vtr_lane = (unsigned)(lg * 1024 + lr * 8);
  unsigned vbuf0 = (unsigned)(size_t)&Vl[0][0];
  unsigned vbuf1 = (unsigned)(size_t)&Vl[1][0];

  // preload tile 0: V staging regs + K fragments (global)
  int4 vreg = *(const int4*)(Vp + (size_t)srow * DH + sseg * 8);
  bf16x8 kf[4][2];
#pragma unroll
  for (int nt = 0; nt < 4; nt++)
#pragma unroll
    for (int kk = 0; kk < 2; kk++)
      kf[nt][kk] = *(const bf16x8*)(Kp + (size_t)(nt * 16 + lr) * DH + kk * 32 + lg * 8);

  for (int kb = 0; kb < NT; ++kb) {
    int cur = kb & 1;
    *(int4*)&Vl[cur][vdst] = vreg;
    if (kb + 1 < NT)
      vreg = *(const int4*)(Vp + (size_t)((kb + 1) * 64 + srow) * DH + sseg * 8);
    __syncthreads();   // V[cur] staged; kb-2 readers proven past barrier(kb-1)

    // QK^T swapped (K in registers): sacc[nt][r] = S[key=nt*16+4lg+r][q=lr]
    f32x4 sacc[4];
#pragma unroll
    for (int nt = 0; nt < 4; nt++) {
      sacc[nt] = zero;
#pragma unroll
      for (int kk = 0; kk < 2; kk++)
        sacc[nt] = __builtin_amdgcn_mfma_f32_16x16x32_bf16(kf[nt][kk], aq[kk], sacc[nt], 0, 0, 0);
    }

    // prefetch K(kb+1) fragments (hides L1/L2 latency under softmax+PV)
    if (kb + 1 < NT) {
      const unsigned short* Kn = Kp + (size_t)(kb + 1) * 64 * DH;
#pragma unroll
      for (int nt = 0; nt < 4; nt++)
#pragma unroll
        for (int kk = 0; kk < 2; kk++)
          kf[nt][kk] = *(const bf16x8*)(Kn + (size_t)(nt * 16 + lr) * DH + kk * 32 + lg * 8);
    }

    // lane-local softmax (base-2)
    float pm;
    {
      float a0 = fmaxf(fmaxf(sacc[0][0], sacc[0][1]), fmaxf(sacc[0][2], sacc[0][3]));
      float a1 = fmaxf(fmaxf(sacc[1][0], sacc[1][1]), fmaxf(sacc[1][2], sacc[1][3]));
      float a2 = fmaxf(fmaxf(sacc[2][0], sacc[2][1]), fmaxf(sacc[2][2], sacc[2][3]));
      float a3 = fmaxf(fmaxf(sacc[3][0], sacc[3][1]), fmaxf(sacc[3][2], sacc[3][3]));
      pm = fmaxf(fmaxf(a0, a1), fmaxf(a2, a3)) * c2;
    }
    pm = fmaxf(pm, __shfl_xor(pm, 16));
    pm = fmaxf(pm, __shfl_xor(pm, 32));

    // T13 defer-max
    if (!__all((int)(pm <= m2 + 8.f))) {
      float mn = fmaxf(m2, pm);
      float corr = fexp2(m2 - mn);
      m2 = mn;
      lsum *= corr;
#pragma unroll
      for (int dt = 0; dt < 4; dt++) {
        f32x4 tmp = o[dt];
        tmp[0] *= corr; tmp[1] *= corr; tmp[2] *= corr; tmp[3] *= corr;
        o[dt] = tmp;
      }
    }

    float p[4][4];
    float rs = 0.f;
#pragma unroll
    for (int nt = 0; nt < 4; nt++)
#pragma unroll
      for (int r = 0; r < 4; r++) {
        float v = fexp2(fmaf(sacc[nt][r], c2, -m2));
        p[nt][r] = v;
        rs += v;
      }
    rs += __shfl_xor(rs, 16);
    rs += __shfl_xor(rs, 32);
    lsum += rs;

    // pack P -> PT[q][key] as b64 (even+odd banks at floor; no barrier needed)
#pragma unroll
    for (int nt = 0; nt < 4; nt++) {
      uint2 w;
      w.x = cvtpk_bf16(p[nt][0], p[nt][1]);
      w.y = cvtpk_bf16(p[nt][2], p[nt][3]);
      *(uint2*)&PT[wave][lr][nt * 16 + lg * 4] = w;
    }

    bf16x8 ap[2];
#pragma unroll
    for (int ks = 0; ks < 2; ks++)
      ap[ks] = *(const bf16x8*)&PT[wave][lr][ks * 32 + lg * 8];

    // PV: O^T += V^T * P^T; V^T fragments via hw transpose reads
    unsigned vb = (cur ? vbuf1 : vbuf0) + vtr_lane;
    union { bf16x8 v; s16x4 hh[2]; } bv[4][2];
#pragma unroll
    for (int dt = 0; dt < 4; dt++)
#pragma unroll
      for (int ks = 0; ks < 2; ks++) {
        tr16(vb + ks * 4096 + 0 * 512 + dt * 128, bv[dt][ks].hh[0]);
        tr16(vb + ks * 4096 + 1 * 512 + dt * 128, bv[dt][ks].hh[1]);
      }
    asm volatile("s_waitcnt lgkmcnt(0)" ::: "memory");
    __builtin_amdgcn_sched_barrier(0);
#pragma unroll
    for (int dt = 0; dt < 4; dt++)
#pragma unroll
      for (int ks = 0; ks < 2; ks++)
        o[dt] = __builtin_amdgcn_mfma_f32_16x16x32_bf16(bv[dt][ks].v, ap[ks], o[dt], 0, 0, 0);
    // no trailing barrier: next tile writes the other V buffer
  }

  // epilogue: normalize, transpose O via PT, coalesced write (r10 pattern)
  float inv = 1.f / lsum;
#pragma unroll
  for (int dt = 0; dt < 4; dt++) {
    uint2 w;
    w.x = cvtpk_bf16(o[dt][0] * inv, o[dt][1] * inv);
    w.y = cvtpk_bf16(o[dt][2] * inv, o[dt][3] * inv);
    *(uint2*)&PT[wave][lr][dt * 16 + lg * 4] = w;
  }

  int row = lane >> 2, cs = lane & 3;
  bf16x8 w0 = *(const bf16x8*)&PT[wave][row][cs * 16];
  bf16x8 w1 = *(const bf16x8*)&PT[wave][row][cs * 16 + 8];
  size_t base = ((size_t)(b * SEQ + q0 + row)) * 512 + h * 64 + cs * 16;
  *(bf16x8*)(CTX + base) = w0;
  *(bf16x8*)(CTX + base + 8) = w1;
}

// ---------------- launch ----------------

extern "C" void kernel_launch(void* const* d_in, const int* in_sizes, int n_in,
                              void* d_out, int out_size, void* d_ws, size_t ws_size,
                              hipStream_t stream) {
  const float* X  = (const float*)d_in[0];
  const float* Wq = (const float*)d_in[1];
  const float* Wk = (const float*)d_in[2];
  const float* Wv = (const float*)d_in[3];
  const float* Wo = (const float*)d_in[4];
  float* out = (float*)d_out;

  char* ws = (char*)d_ws;
  unsigned short* Wqt = (unsigned short*)(ws);
  unsigned short* Wot = (unsigned short*)(ws + 3u * 524288u);
  unsigned short* Xb  = (unsigned short*)(ws + 4u * 524288u);
  unsigned short* Qb  = (unsigned short*)(ws + 4u * 524288u + 8388608u);
  unsigned short* Kb  = Qb + (size_t)MTOT * 512;
  unsigned short* Vb  = Kb + (size_t)MTOT * 512;
  unsigned short* CTX = Vb + (size_t)MTOT * 512;

  int nX = MTOT * D_MODEL;
  cvt_x_kernel<<<dim3(nX / (8 * 256)), dim3(256), 0, stream>>>(X, Xb, nX);
  cvt_w_kernel<<<dim3(1024, 4), dim3(256), 0, stream>>>(Wq, Wk, Wv, Wo, Wqt);
  gemm128_kernel<<<dim3(64, 4, 3), dim3(256), 0, stream>>>(Xb, Wqt, Qb, nullptr, -1);
  attn_kernel<<<dim3(512), dim3(512), 0, stream>>>(Qb, Kb, Vb, CTX);
  gemm128_kernel<<<dim3(64, 4, 1), dim3(256), 0, stream>>>(CTX, Wot, nullptr, out, 3);
}

// Round 15
// 189.297 us; speedup vs baseline: 1.6324x; 1.6324x over previous
//
#include <hip/hip_runtime.h>

#define D_MODEL 512
#define NHEADS 8
#define DH 64
#define BATCH 2
#define SEQ 4096
#define MTOT (BATCH*SEQ)   // 8192

typedef __attribute__((ext_vector_type(8))) short bf16x8;
typedef __attribute__((ext_vector_type(4))) short s16x4;
typedef __attribute__((ext_vector_type(4))) float f32x4;

__device__ __forceinline__ unsigned short f2b(float f) {
  unsigned int u = __float_as_uint(f);
  u = (u + 0x7fffu + ((u >> 16) & 1u)) >> 16;
  return (unsigned short)u;
}

__device__ __forceinline__ float fexp2(float x) {
  return __builtin_amdgcn_exp2f(x);
}

// pack 2 f32 -> 2 bf16 in one u32 (lo = a, hi = b)
__device__ __forceinline__ unsigned int cvtpk_bf16(float a, float b) {
  unsigned int r;
  asm("v_cvt_pk_bf16_f32 %0, %1, %2" : "=v"(r) : "v"(a), "v"(b));
  return r;
}

// hardware transpose read: tile_base = addr & ~127 (4x16 bf16 row-major tile),
// col = (addr>>3)&15; lane receives the 4 bf16 of that column. (r10-verified)
__device__ __forceinline__ void tr16(unsigned addr, s16x4& d) {
  asm volatile("ds_read_b64_tr_b16 %0, %1" : "=v"(d) : "v"(addr));
}

// ---------------- conversion kernels ----------------

__global__ void cvt_x_kernel(const float* __restrict__ X,
                             unsigned short* __restrict__ Xb, int n) {
  int i = (blockIdx.x * blockDim.x + threadIdx.x) * 8;
  if (i >= n) return;
  const float4* s = (const float4*)(X + i);
  float4 v0 = s[0], v1 = s[1];
  union { bf16x8 v; unsigned short u[8]; } r;
  r.u[0] = f2b(v0.x); r.u[1] = f2b(v0.y); r.u[2] = f2b(v0.z); r.u[3] = f2b(v0.w);
  r.u[4] = f2b(v1.x); r.u[5] = f2b(v1.y); r.u[6] = f2b(v1.z); r.u[7] = f2b(v1.w);
  *(bf16x8*)(Xb + i) = r.v;
}

__global__ void cvt_w_kernel(const float* __restrict__ W0, const float* __restrict__ W1,
                             const float* __restrict__ W2, const float* __restrict__ W3,
                             unsigned short* __restrict__ Wt) {
  const float* Ws[4] = {W0, W1, W2, W3};
  const float* W = Ws[blockIdx.y];
  int t = blockIdx.x * blockDim.x + threadIdx.x;
  int k = t >> 9, n = t & 511;
  Wt[(size_t)blockIdx.y * (512*512) + (size_t)n * 512 + k] = f2b(W[t]);
}

// ---------------- 128x128 bf16 MFMA GEMM ----------------
__global__ __launch_bounds__(256) void gemm128_kernel(
    const unsigned short* __restrict__ A,
    const unsigned short* __restrict__ WtAll,
    unsigned short* __restrict__ qkv,
    float* __restrict__ outF,
    int modeParam) {
  int mode = (modeParam < 0) ? (int)blockIdx.z : modeParam;
  const unsigned short* Wt = WtAll + (size_t)((modeParam < 0) ? blockIdx.z : 0) * (512*512);

  __shared__ __align__(16) unsigned short Alds[128][72];
  __shared__ __align__(16) unsigned short Blds[128][72];

  int t = threadIdx.x;
  int lane = t & 63, wave = t >> 6;
  int wr = wave >> 1, wc = wave & 1;
  int lr = lane & 15, lg = lane >> 4;
  int mBase = blockIdx.x * 128;
  int nBase = blockIdx.y * 128;

  f32x4 zero = {0.f, 0.f, 0.f, 0.f};
  f32x4 acc[4][4];
#pragma unroll
  for (int i = 0; i < 4; i++)
#pragma unroll
    for (int j = 0; j < 4; j++) acc[i][j] = zero;

  int seg = t & 7, r0 = t >> 3;

  for (int k0 = 0; k0 < 512; k0 += 64) {
#pragma unroll
    for (int p = 0; p < 4; ++p) {
      int row = r0 + p * 32;
      *(int4*)&Alds[row][seg * 8] =
          *(const int4*)(A + (size_t)(mBase + row) * 512 + k0 + seg * 8);
      *(int4*)&Blds[row][seg * 8] =
          *(const int4*)(Wt + (size_t)(nBase + row) * 512 + k0 + seg * 8);
    }
    __syncthreads();
#pragma unroll
    for (int kk = 0; kk < 64; kk += 32) {
      bf16x8 afr[4], bfr[4];
#pragma unroll
      for (int mi = 0; mi < 4; mi++)
        afr[mi] = *(const bf16x8*)&Alds[wr * 64 + mi * 16 + lr][kk + lg * 8];
#pragma unroll
      for (int ni = 0; ni < 4; ni++)
        bfr[ni] = *(const bf16x8*)&Blds[wc * 64 + ni * 16 + lr][kk + lg * 8];
#pragma unroll
      for (int mi = 0; mi < 4; mi++)
#pragma unroll
        for (int ni = 0; ni < 4; ni++)
          acc[mi][ni] = __builtin_amdgcn_mfma_f32_16x16x32_bf16(
              afr[mi], bfr[ni], acc[mi][ni], 0, 0, 0);
    }
    __syncthreads();
  }

#pragma unroll
  for (int mi = 0; mi < 4; mi++) {
#pragma unroll
    for (int ni = 0; ni < 4; ni++) {
#pragma unroll
      for (int rg = 0; rg < 4; rg++) {
        int r = mBase + wr * 64 + mi * 16 + lg * 4 + rg;
        int c = nBase + wc * 64 + ni * 16 + lr;
        float v = acc[mi][ni][rg];
        if (mode < 3) {
          int b = r >> 12, s = r & 4095, h = c >> 6, d = c & 63;
          qkv[(size_t)mode * ((size_t)MTOT * 512) +
              ((((size_t)b * NHEADS + h) * SEQ + s) * DH + d)] = f2b(v);
        } else {
          outF[(size_t)r * 512 + c] = v;
        }
      }
    }
  }
}

// ---------------- flash attention (r10-proven structure + b64 PT + setprio) --
// grid 512 flat, block 512 (8 waves), 16 q-rows/wave. KV tiles of 64 keys,
// K row-major LDS + V subtiled LDS, double-buffered; ONE barrier per tile.
// Swapped-QK lane-local softmax; T13 defer-max; tr16 V fragments; T5 setprio
// around MFMA clusters.
__global__ __launch_bounds__(512) void attn_kernel(
    const unsigned short* __restrict__ Qb,
    const unsigned short* __restrict__ Kb,
    const unsigned short* __restrict__ Vb,
    unsigned short* __restrict__ CTX) {
  int flat = blockIdx.x;
  int xcd = flat & 7, jj = flat >> 3;
  int bh = xcd + ((jj >> 5) << 3);   // 2 heads per XCD, bijective (512%8==0)
  int qc = jj & 31;
  int b = bh >> 3, h = bh & 7;
  const unsigned short* Qp = Qb + (size_t)bh * SEQ * DH;
  const unsigned short* Kp = Kb + (size_t)bh * SEQ * DH;
  const unsigned short* Vp = Vb + (size_t)bh * SEQ * DH;

  __shared__ __align__(128) unsigned short Kl[2][64][72];   // 18432 B
  __shared__ __align__(128) unsigned short Vl[2][4096];     // 16384 B
  __shared__ __align__(128) unsigned short PT[8][16][72];   // 18432 B

  int t = threadIdx.x;            // 0..511
  int lane = t & 63, wave = t >> 6;
  int lr = lane & 15, lg = lane >> 4;
  int q0 = qc * 128 + wave * 16;

  // Q fragments (B operand): col=q=lr, k = kk*32 + 8*lg + j
  bf16x8 aq[2];
#pragma unroll
  for (int kk = 0; kk < 2; ++kk)
    aq[kk] = *(const bf16x8*)(Qp + (size_t)(q0 + lr) * DH + kk * 32 + lg * 8);

  f32x4 zero = {0.f, 0.f, 0.f, 0.f};
  f32x4 o[4];
#pragma unroll
  for (int dt = 0; dt < 4; dt++) o[dt] = zero;
  float m2 = -1e30f, lsum = 0.f;

  const float c2 = 0.125f * 1.44269504088896340736f;

  // V staging: 512 threads, ONE b128 each: row = t>>3, seg = t&7
  int srow = t >> 3, sseg = t & 7;
  int vdst = ((srow >> 2) * 4 + (sseg >> 1)) * 64 + (srow & 3) * 16 + (sseg & 1) * 8;
  const int NT = SEQ / 64;

  unsigned vtr_lane = (unsigned)(lg * 1024 + lr * 8);
  unsigned vbuf0 = (unsigned)(size_t)&Vl[0][0];
  unsigned vbuf1 = (unsigned)(size_t)&Vl[1][0];

  // preload tile 0
  int4 kreg = *(const int4*)(Kp + (size_t)srow * DH + sseg * 8);
  int4 vreg = *(const int4*)(Vp + (size_t)srow * DH + sseg * 8);

  for (int kb = 0; kb < NT; ++kb) {
    int cur = kb & 1;
    *(int4*)&Kl[cur][srow][sseg * 8] = kreg;
    *(int4*)&Vl[cur][vdst] = vreg;
    if (kb + 1 < NT) {
      kreg = *(const int4*)(Kp + (size_t)((kb + 1) * 64 + srow) * DH + sseg * 8);
      vreg = *(const int4*)(Vp + (size_t)((kb + 1) * 64 + srow) * DH + sseg * 8);
    }
    __syncthreads();   // buf[cur] staged; kb-2 readers proven past barrier(kb-1)

    // QK^T swapped: sacc[nt][r] = S[key = nt*16 + 4*lg + r][q = lr]
    f32x4 sacc[4];
    __builtin_amdgcn_s_setprio(1);
#pragma unroll
    for (int nt = 0; nt < 4; nt++) {
      sacc[nt] = zero;
#pragma unroll
      for (int kk = 0; kk < 2; kk++) {
        bf16x8 bk = *(const bf16x8*)&Kl[cur][nt * 16 + lr][kk * 32 + lg * 8];
        sacc[nt] = __builtin_amdgcn_mfma_f32_16x16x32_bf16(bk, aq[kk], sacc[nt], 0, 0, 0);
      }
    }
    __builtin_amdgcn_s_setprio(0);

    // lane-local softmax (base-2)
    float pm;
    {
      float a0 = fmaxf(fmaxf(sacc[0][0], sacc[0][1]), fmaxf(sacc[0][2], sacc[0][3]));
      float a1 = fmaxf(fmaxf(sacc[1][0], sacc[1][1]), fmaxf(sacc[1][2], sacc[1][3]));
      float a2 = fmaxf(fmaxf(sacc[2][0], sacc[2][1]), fmaxf(sacc[2][2], sacc[2][3]));
      float a3 = fmaxf(fmaxf(sacc[3][0], sacc[3][1]), fmaxf(sacc[3][2], sacc[3][3]));
      pm = fmaxf(fmaxf(a0, a1), fmaxf(a2, a3)) * c2;
    }
    pm = fmaxf(pm, __shfl_xor(pm, 16));
    pm = fmaxf(pm, __shfl_xor(pm, 32));

    // T13 defer-max
    if (!__all((int)(pm <= m2 + 8.f))) {
      float mn = fmaxf(m2, pm);
      float corr = fexp2(m2 - mn);
      m2 = mn;
      lsum *= corr;
#pragma unroll
      for (int dt = 0; dt < 4; dt++) {
        f32x4 tmp = o[dt];
        tmp[0] *= corr; tmp[1] *= corr; tmp[2] *= corr; tmp[3] *= corr;
        o[dt] = tmp;
      }
    }

    float p[4][4];
    float rs = 0.f;
#pragma unroll
    for (int nt = 0; nt < 4; nt++)
#pragma unroll
      for (int r = 0; r < 4; r++) {
        float v = fexp2(fmaf(sacc[nt][r], c2, -m2));
        p[nt][r] = v;
        rs += v;
      }
    rs += __shfl_xor(rs, 16);
    rs += __shfl_xor(rs, 32);
    lsum += rs;

    // pack P -> PT[q][key] as b64 (per-wave; intra-wave in-order, no barrier)
#pragma unroll
    for (int nt = 0; nt < 4; nt++) {
      uint2 w;
      w.x = cvtpk_bf16(p[nt][0], p[nt][1]);
      w.y = cvtpk_bf16(p[nt][2], p[nt][3]);
      *(uint2*)&PT[wave][lr][nt * 16 + lg * 4] = w;
    }

    bf16x8 ap[2];
#pragma unroll
    for (int ks = 0; ks < 2; ks++)
      ap[ks] = *(const bf16x8*)&PT[wave][lr][ks * 32 + lg * 8];

    // PV: O^T += V^T * P^T; V^T fragments via hw transpose reads
    unsigned vb = (cur ? vbuf1 : vbuf0) + vtr_lane;
    union { bf16x8 v; s16x4 hh[2]; } bv[4][2];
#pragma unroll
    for (int dt = 0; dt < 4; dt++)
#pragma unroll
      for (int ks = 0; ks < 2; ks++) {
        tr16(vb + ks * 4096 + 0 * 512 + dt * 128, bv[dt][ks].hh[0]);
        tr16(vb + ks * 4096 + 1 * 512 + dt * 128, bv[dt][ks].hh[1]);
      }
    asm volatile("s_waitcnt lgkmcnt(0)" ::: "memory");
    __builtin_amdgcn_sched_barrier(0);
    __builtin_amdgcn_s_setprio(1);
#pragma unroll
    for (int dt = 0; dt < 4; dt++)
#pragma unroll
      for (int ks = 0; ks < 2; ks++)
        o[dt] = __builtin_amdgcn_mfma_f32_16x16x32_bf16(bv[dt][ks].v, ap[ks], o[dt], 0, 0, 0);
    __builtin_amdgcn_s_setprio(0);
    // no trailing barrier: next tile writes the other buffer
  }

  // epilogue: normalize, transpose O via PT, coalesced write
  float inv = 1.f / lsum;
#pragma unroll
  for (int dt = 0; dt < 4; dt++) {
    uint2 w;
    w.x = cvtpk_bf16(o[dt][0] * inv, o[dt][1] * inv);
    w.y = cvtpk_bf16(o[dt][2] * inv, o[dt][3] * inv);
    *(uint2*)&PT[wave][lr][dt * 16 + lg * 4] = w;
  }

  int row = lane >> 2, cs = lane & 3;
  bf16x8 w0 = *(const bf16x8*)&PT[wave][row][cs * 16];
  bf16x8 w1 = *(const bf16x8*)&PT[wave][row][cs * 16 + 8];
  size_t base = ((size_t)(b * SEQ + q0 + row)) * 512 + h * 64 + cs * 16;
  *(bf16x8*)(CTX + base) = w0;
  *(bf16x8*)(CTX + base + 8) = w1;
}

// ---------------- launch ----------------

extern "C" void kernel_launch(void* const* d_in, const int* in_sizes, int n_in,
                              void* d_out, int out_size, void* d_ws, size_t ws_size,
                              hipStream_t stream) {
  const float* X  = (const float*)d_in[0];
  const float* Wq = (const float*)d_in[1];
  const float* Wk = (const float*)d_in[2];
  const float* Wv = (const float*)d_in[3];
  const float* Wo = (const float*)d_in[4];
  float* out = (float*)d_out;

  char* ws = (char*)d_ws;
  unsigned short* Wqt = (unsigned short*)(ws);
  unsigned short* Wot = (unsigned short*)(ws + 3u * 524288u);
  unsigned short* Xb  = (unsigned short*)(ws + 4u * 524288u);
  unsigned short* Qb  = (unsigned short*)(ws + 4u * 524288u + 8388608u);
  unsigned short* Kb  = Qb + (size_t)MTOT * 512;
  unsigned short* Vb  = Kb + (size_t)MTOT * 512;
  unsigned short* CTX = Vb + (size_t)MTOT * 512;

  int nX = MTOT * D_MODEL;
  cvt_x_kernel<<<dim3(nX / (8 * 256)), dim3(256), 0, stream>>>(X, Xb, nX);
  cvt_w_kernel<<<dim3(1024, 4), dim3(256), 0, stream>>>(Wq, Wk, Wv, Wo, Wqt);
  gemm128_kernel<<<dim3(64, 4, 3), dim3(256), 0, stream>>>(Xb, Wqt, Qb, nullptr, -1);
  attn_kernel<<<dim3(512), dim3(512), 0, stream>>>(Qb, Kb, Vb, CTX);
  gemm128_kernel<<<dim3(64, 4, 1), dim3(256), 0, stream>>>(CTX, Wot, nullptr, out, 3);
}